// Round 1
// baseline (256.128 us; speedup 1.0000x reference)
//
#include <hip/hip_runtime.h>

// Problem: weights_i = exp(F_i·w) / segsum_{pid}(exp(F·w))
//   F: [N,128] fp32 (1.024 GB — the HBM floor), w: [128] fp32,
//   pid: [N] int32 in [0,S), out: [N] fp32.
//
// Kernel 1: per-wave dot products, 2 rows/iter (float4/lane = 1KB/wave load),
//           butterfly reduce within 32-lane halves, exp, scatter-atomicAdd
//           into partition[S] (L2-resident, ~20 collisions/bin avg).
// Kernel 2: out = logit / partition[pid], vectorized x4.

__global__ void logit_partition_kernel(const float4* __restrict__ F4,
                                       const float* __restrict__ w,
                                       const int* __restrict__ pid,
                                       float* __restrict__ logit,
                                       float* __restrict__ part,
                                       int nrows) {
    const int lane = threadIdx.x & 63;
    const int l32  = lane & 31;   // lane within 32-half
    const int half = lane >> 5;   // which of the 2 rows this lane works on
    const int wave  = (blockIdx.x * blockDim.x + threadIdx.x) >> 6;
    const int nwave = (gridDim.x * blockDim.x) >> 6;

    // w fragment: lane l32 holds w[4*l32 .. 4*l32+3]; wave-invariant per lane.
    const float4 wf = reinterpret_cast<const float4*>(w)[l32];

    for (int r = wave * 2; r < nrows; r += nwave * 2) {
        const int row = r + half;
        if (row < nrows) {
            // lanes 0..31 -> row r (contiguous 512B); lanes 32..63 -> row r+1.
            float4 f = F4[(size_t)row * 32 + l32];
            float s = f.x * wf.x + f.y * wf.y + f.z * wf.z + f.w * wf.w;
            // butterfly reduce within each 32-lane half (offsets <=16 stay in-half)
            #pragma unroll
            for (int o = 16; o; o >>= 1) s += __shfl_xor(s, o, 64);
            if (l32 == 0) {
                float lg = expf(s);
                logit[row] = lg;
                atomicAdd(&part[pid[row]], lg);  // device-scope by default
            }
        }
    }
}

__global__ void weights_kernel(const float4* __restrict__ logit4,
                               const int4* __restrict__ pid4,
                               const float* __restrict__ part,
                               float4* __restrict__ out4,
                               int nvec,
                               const float* __restrict__ logit,
                               const int* __restrict__ pid,
                               float* __restrict__ out,
                               int n) {
    int i = blockIdx.x * blockDim.x + threadIdx.x;
    const int stride = gridDim.x * blockDim.x;
    for (; i < nvec; i += stride) {
        float4 lg = logit4[i];
        int4 p = pid4[i];
        float4 o;
        o.x = lg.x / part[p.x];
        o.y = lg.y / part[p.y];
        o.z = lg.z / part[p.z];
        o.w = lg.w / part[p.w];
        out4[i] = o;
    }
    // scalar tail (N % 4), done by one thread — N=2M is divisible by 4 so
    // this is normally empty.
    if (blockIdx.x == 0 && threadIdx.x == 0) {
        for (int j = nvec * 4; j < n; ++j) out[j] = logit[j] / part[pid[j]];
    }
}

extern "C" void kernel_launch(void* const* d_in, const int* in_sizes, int n_in,
                              void* d_out, int out_size, void* d_ws, size_t ws_size,
                              hipStream_t stream) {
    const float* features = (const float*)d_in[0];   // [N,128]
    const float* w        = (const float*)d_in[1];   // [128]
    const int*   pid      = (const int*)d_in[2];     // [N]
    // d_in[3] = unique_phrase (arange(S)) — only its size matters.

    const int N = in_sizes[2];
    const int S = in_sizes[3];

    float* logit = (float*)d_ws;            // N floats (8 MB)
    float* part  = logit + N;               // S floats (400 KB)
    float* out   = (float*)d_out;

    // zero the partition bins (ws is poisoned to 0xAA once; must re-zero
    // every call for graph-replay determinism)
    hipMemsetAsync(part, 0, (size_t)S * sizeof(float), stream);

    // Kernel 1: 2048 blocks x 256 thr = 8192 waves = 32 waves/CU (max occ).
    {
        dim3 grid(2048), block(256);
        logit_partition_kernel<<<grid, block, 0, stream>>>(
            (const float4*)features, w, pid, logit, part, N);
    }

    // Kernel 2: vectorized divide+gather.
    {
        const int nvec = N / 4;
        int blocks = (nvec + 255) / 256;
        if (blocks > 2048) blocks = 2048;
        weights_kernel<<<dim3(blocks), dim3(256), 0, stream>>>(
            (const float4*)logit, (const int4*)pid, part, (float4*)out, nvec,
            logit, pid, out, N);
    }
}

// Round 2
// 229.796 us; speedup vs baseline: 1.1146x; 1.1146x over previous
//
#include <hip/hip_runtime.h>

// weights_i = exp(F_i·w) / segsum_{pid}(exp(F·w))
//   F: [N,128] fp32 (1.024 GB — the HBM floor), w: [128], pid: [N] int32,
//   out: [N] fp32.
//
// Kernel 1 (restructured R1): 16 rows / wave / macro-iteration.
//   - 8 independent float4 wave-loads (8 KB in flight) -> 8x MLP vs R0.
//   - select-merge shuffle tree: 16 shuffles per 16 rows (was 2.5/row),
//     ends with 16 owner lanes -> exp/atomic/store at 16 active lanes
//     (8x fewer atomic instructions than R0's 2-active-lane version).
// Kernel 2: out = logit / partition[pid], float4-vectorized (~5 us).

__global__ void logit_partition_kernel(const float4* __restrict__ F4,
                                       const float* __restrict__ w,
                                       const int* __restrict__ pid,
                                       float* __restrict__ logit,
                                       float* __restrict__ part,
                                       int nrows) {
    const int lane = threadIdx.x & 63;
    const int l32  = lane & 31;
    const int half = lane >> 5;
    const int wave  = (blockIdx.x * blockDim.x + threadIdx.x) >> 6;
    const int nwave = (gridDim.x * blockDim.x) >> 6;

    // lane l32 holds w[4*l32 .. 4*l32+3]
    const float4 wf = reinterpret_cast<const float4*>(w)[l32];

    const int ntile = nrows / 16;          // full 16-row tiles
    const int nmain = ntile * 16;

    for (int t = wave; t < ntile; t += nwave) {
        const int r = t * 16;

        // ---- 8 independent 1KB wave-loads: rows r .. r+15 ----
        // load j covers rows (r+2j, r+2j+1); half 0 -> even row, half 1 -> odd.
        float4 f[8];
        #pragma unroll
        for (int j = 0; j < 8; ++j)
            f[j] = F4[(size_t)(r + 2 * j + half) * 32 + l32];

        float s[8];
        #pragma unroll
        for (int j = 0; j < 8; ++j)
            s[j] = f[j].x * wf.x + f[j].y * wf.y + f[j].z * wf.z + f[j].w * wf.w;

        // ---- select-merge reduction within each 32-lane half ----
        // merge(a,b,mask): lanes with (l32&mask)==0 keep a-reduced, else b-reduced
        float m[4];
        #pragma unroll
        for (int j = 0; j < 4; ++j) {
            float u = s[2*j]   + __shfl_xor(s[2*j],   16, 64);
            float v = s[2*j+1] + __shfl_xor(s[2*j+1], 16, 64);
            m[j] = (l32 & 16) ? v : u;
        }
        float n[2];
        #pragma unroll
        for (int j = 0; j < 2; ++j) {
            float u = m[2*j]   + __shfl_xor(m[2*j],   8, 64);
            float v = m[2*j+1] + __shfl_xor(m[2*j+1], 8, 64);
            n[j] = (l32 & 8) ? v : u;
        }
        float u = n[0] + __shfl_xor(n[0], 4, 64);
        float v = n[1] + __shfl_xor(n[1], 4, 64);
        float tt = (l32 & 4) ? v : u;
        tt += __shfl_xor(tt, 2, 64);
        tt += __shfl_xor(tt, 1, 64);

        // lane's s-index: j = 4*bit2 + 2*bit3 + bit4 of l32
        // owners: (l32 & 3) == 0  -> 16 owner lanes per wave (8 per half)
        if ((l32 & 3) == 0) {
            const int jidx = ((l32 >> 2) & 1) * 4 + ((l32 >> 3) & 1) * 2 +
                             ((l32 >> 4) & 1);
            const int row = r + 2 * jidx + half;
            float lg = expf(tt);
            logit[row] = lg;
            atomicAdd(&part[pid[row]], lg);
        }
    }

    // ---- tail rows [nmain, nrows): R0-style 2 rows per wave ----
    for (int r = nmain + wave * 2; r < nrows; r += nwave * 2) {
        const int row = r + half;
        if (row < nrows) {
            float4 f = F4[(size_t)row * 32 + l32];
            float s = f.x * wf.x + f.y * wf.y + f.z * wf.z + f.w * wf.w;
            #pragma unroll
            for (int o = 16; o; o >>= 1) s += __shfl_xor(s, o, 64);
            if (l32 == 0) {
                float lg = expf(s);
                logit[row] = lg;
                atomicAdd(&part[pid[row]], lg);
            }
        }
    }
}

__global__ void weights_kernel(const float4* __restrict__ logit4,
                               const int4* __restrict__ pid4,
                               const float* __restrict__ part,
                               float4* __restrict__ out4,
                               int nvec,
                               const float* __restrict__ logit,
                               const int* __restrict__ pid,
                               float* __restrict__ out,
                               int n) {
    int i = blockIdx.x * blockDim.x + threadIdx.x;
    const int stride = gridDim.x * blockDim.x;
    for (; i < nvec; i += stride) {
        float4 lg = logit4[i];
        int4 p = pid4[i];
        float4 o;
        o.x = lg.x / part[p.x];
        o.y = lg.y / part[p.y];
        o.z = lg.z / part[p.z];
        o.w = lg.w / part[p.w];
        out4[i] = o;
    }
    if (blockIdx.x == 0 && threadIdx.x == 0) {
        for (int j = nvec * 4; j < n; ++j) out[j] = logit[j] / part[pid[j]];
    }
}

extern "C" void kernel_launch(void* const* d_in, const int* in_sizes, int n_in,
                              void* d_out, int out_size, void* d_ws, size_t ws_size,
                              hipStream_t stream) {
    const float* features = (const float*)d_in[0];   // [N,128]
    const float* w        = (const float*)d_in[1];   // [128]
    const int*   pid      = (const int*)d_in[2];     // [N]

    const int N = in_sizes[2];
    const int S = in_sizes[3];

    float* logit = (float*)d_ws;            // N floats
    float* part  = logit + N;               // S floats
    float* out   = (float*)d_out;

    // re-zero partition bins every call (graph-replay determinism)
    hipMemsetAsync(part, 0, (size_t)S * sizeof(float), stream);

    // Kernel 1: 2048 blocks x 256 thr = 8192 waves (32 waves/CU)
    logit_partition_kernel<<<dim3(2048), dim3(256), 0, stream>>>(
        (const float4*)features, w, pid, logit, part, N);

    // Kernel 2: vectorized divide+gather
    {
        const int nvec = N / 4;
        int blocks = (nvec + 255) / 256;
        if (blocks > 2048) blocks = 2048;
        weights_kernel<<<dim3(blocks), dim3(256), 0, stream>>>(
            (const float4*)logit, (const int4*)pid, part, (float4*)out, nvec,
            logit, pid, out, N);
    }
}